// Round 1
// baseline (200.130 us; speedup 1.0000x reference)
//
#include <hip/hip_runtime.h>

#define NT 8
#define NY 32
#define NX 32
#define NN 1024  // NY*NX

// Compute the 9 stencil coefficients of M = I + A for one node, plus w = 1/tau^2.
// c[idx] with idx = (ry+1)*3 + (rx+1) for target offset (ry, rx); coefficient is
// zeroed when the TARGET node (iy+ry, ix+rx) falls outside the grid (matches the
// reference's `valid` masking, which tests the column node).
__device__ __forceinline__ void node_coefs(const float* __restrict__ kap,
                                           const float* __restrict__ m,
                                           const float* __restrict__ H,
                                           const float* __restrict__ tau,
                                           int b, int node, int tc,
                                           int iy, int ix,
                                           float* c /*[9]*/, float& w) {
    const int base = node * NT + tc;                 // [.., node, t] layout, last dim NT
    const float kp  = kap[(b * NN) * NT + base];     // kappa[b,0,node,t]
    const float m1  = m[((b * 2 + 0) * NN) * NT + base];
    const float m2  = m[((b * 2 + 1) * NN) * NT + base];
    const float h11 = H[((b * 4 + 0) * NN) * NT + base];  // H[b,0,0]
    const float h12 = H[((b * 4 + 1) * NN) * NT + base];  // H[b,0,1]
    const float h22 = H[((b * 4 + 3) * NN) * NT + base];  // H[b,1,1]
    const float tv  = tau[(b * NN) * NT + base];
    w = 1.0f / (tv * tv);

    const float cxy = 0.5f * h12;
    const bool ym = (iy - 1) >= 0, yp = (iy + 1) < NY;
    const bool xm = (ix - 1) >= 0, xp = (ix + 1) < NX;

    c[4] = 1.0f + kp * kp + 2.0f * h11 + 2.0f * h22;      // center: I + diag(A)
    c[0] = (ym && xm) ? -cxy               : 0.0f;        // (-1,-1)
    c[1] =  ym        ? (-h22 - 0.5f * m2) : 0.0f;        // (-1, 0)
    c[2] = (ym && xp) ?  cxy               : 0.0f;        // (-1,+1)
    c[3] =  xm        ? (-h11 - 0.5f * m1) : 0.0f;        // ( 0,-1)
    c[5] =  xp        ? (-h11 + 0.5f * m1) : 0.0f;        // ( 0,+1)
    c[6] = (yp && xm) ?  cxy               : 0.0f;        // (+1,-1)
    c[7] =  yp        ? (-h22 + 0.5f * m2) : 0.0f;        // (+1, 0)
    c[8] = (yp && xp) ? -cxy               : 0.0f;        // (+1,+1)
}

// One block per output row. Output layout: out[b][blk][t][j][k], row-major,
// row index = ((b*3 + blk)*NT + t)*NN + j == blockIdx.x.
__global__ __launch_bounds__(256) void spde_kernel(const float* __restrict__ kap,
                                                   const float* __restrict__ m,
                                                   const float* __restrict__ H,
                                                   const float* __restrict__ tau,
                                                   float* __restrict__ out) {
    __shared__ float sc[9][9];   // sc[d][r]: coef of node j+offset_d, target offset r
    __shared__ float sw[9];      // w = 1/tau^2 at node j+offset_d (0 if off-grid)
    __shared__ float vals[25];   // the row's nonzero window values

    const int row = blockIdx.x;
    const int j   = row & (NN - 1);
    const int t   = (row >> 10) & 7;
    const int bb  = row >> 13;          // b*3 + blk
    const int blk = bb % 3;
    const int b   = bb / 3;
    const int jy = j >> 5, jx = j & 31;
    const int tid = threadIdx.x;

    const bool zero_row = (blk == 1 && t == 0) || (blk == 2 && t == NT - 1);

    if (!zero_row) {
        const int tc = (blk == 2) ? t + 1 : t;   // upper uses time t+1 coefficients

        if (tid < 9) {  // phase 0: stencil coefs of the 9 neighborhood nodes
            const int ey = tid / 3 - 1, ex = tid % 3 - 1;
            const int iy = jy + ey, ix = jx + ex;
            float c[9];
            float w = 0.0f;
            if (iy >= 0 && iy < NY && ix >= 0 && ix < NX) {
                node_coefs(kap, m, H, tau, b, iy * NX + ix, tc, iy, ix, c, w);
            } else {
                #pragma unroll
                for (int q = 0; q < 9; ++q) c[q] = 0.0f;
            }
            #pragma unroll
            for (int q = 0; q < 9; ++q) sc[tid][q] = c[q];
            sw[tid] = w;
        }
        __syncthreads();

        if (blk == 0) {  // D row: P[j, j+(dy,dx)] over 5x5 window
            if (tid < 25) {
                const int dy = tid / 5 - 2, dx = tid % 5 - 2;
                float acc = 0.0f;
                #pragma unroll
                for (int d = 0; d < 9; ++d) {
                    const int ey = d / 3 - 1, ex = d % 3 - 1;
                    const int r2y = dy - ey, r2x = dx - ex;
                    if (r2y >= -1 && r2y <= 1 && r2x >= -1 && r2x <= 1) {
                        // w_i * M[i,j] * M[i,k]; M[i,j] = sc[d][8-d] (target offset -offset_d)
                        acc += sw[d] * sc[d][8 - d] * sc[d][(r2y + 1) * 3 + (r2x + 1)];
                    }
                }
                if (tid == 12 && t < NT - 1) {  // diagonal: + w_{t+1}[j]
                    const float tv = tau[(size_t)(b * NN + j) * NT + (t + 1)];
                    acc += 1.0f / (tv * tv);
                }
                vals[tid] = acc;
            }
        } else if (blk == 1) {  // lower[t][j,k] = -w_t[k] * M_t[k,j], k = j+(dy,dx)
            if (tid < 9) {
                vals[tid] = -sw[tid] * sc[tid][8 - tid];
            }
        } else {                // upper[t][j,k] = -w_{t+1}[j] * M_{t+1}[j,k]
            if (tid < 9) {
                vals[tid] = -sw[4] * sc[4][tid];
            }
        }
        __syncthreads();
    }

    // phase 2: every thread writes one coalesced float4 (columns 4*tid .. 4*tid+3)
    float4 v = make_float4(0.f, 0.f, 0.f, 0.f);
    if (!zero_row) {
        const int R = (blk == 0) ? 2 : 1;
        const int W = 2 * R + 1;
        const int c0 = tid * 4;
        float* vp = &v.x;
        #pragma unroll
        for (int q = 0; q < 4; ++q) {
            const int c = c0 + q;
            const int cy = c >> 5, cx = c & 31;
            const int ddy = cy - jy, ddx = cx - jx;
            if (ddy >= -R && ddy <= R && ddx >= -R && ddx <= R) {
                v = v;  // keep compiler from reordering oddly (no-op)
                vp[q] = vals[(ddy + R) * W + (ddx + R)];
            }
        }
    }
    float4* op = (float4*)(out + (size_t)row * NN);
    op[tid] = v;
}

extern "C" void kernel_launch(void* const* d_in, const int* in_sizes, int n_in,
                              void* d_out, int out_size, void* d_ws, size_t ws_size,
                              hipStream_t stream) {
    const float* kap = (const float*)d_in[0];  // [n_b,1,N,NT]
    const float* m   = (const float*)d_in[1];  // [n_b,2,N,NT]
    const float* H   = (const float*)d_in[2];  // [n_b,2,2,N,NT]
    const float* tau = (const float*)d_in[3];  // [n_b,1,N,NT]
    float* out = (float*)d_out;                // [n_b,3,NT,N,N]

    const int n_b = in_sizes[0] / (NN * NT);
    const int grid = n_b * 3 * NT * NN;        // one block per output row
    spde_kernel<<<grid, 256, 0, stream>>>(kap, m, H, tau, out);
}